// Round 1
// baseline (119.613 us; speedup 1.0000x reference)
//
#include <hip/hip_runtime.h>
#include <stdint.h>

#define G_NUM 4096
#define BLOCK 256
#define CAP   3072   // staged keys per segment (mean seg len 2048, sd ~45)

__device__ __forceinline__ unsigned int order_bits(float f) {
    unsigned int b = __float_as_uint(f);
    return (b & 0x80000000u) ? ~b : (b | 0x80000000u);
}

// flag: 0 = int32 mask, 1 = float mask, 2 = byte (bool) mask
__global__ void detect_mask_kernel(const unsigned int* __restrict__ m, int* __restrict__ flag) {
    if (blockIdx.x == 0 && threadIdx.x == 0) {
        bool allI = true, allF = true;
        for (int i = 0; i < 256; ++i) {
            unsigned int w = m[i];
            if (w > 1u) allI = false;
            if (w != 0u && w != 0x3F800000u) allF = false;
        }
        *flag = allI ? 0 : (allF ? 1 : 2);
    }
}

__global__ void seg_starts_kernel(const int* __restrict__ batch, int* __restrict__ start, int E) {
    int i = blockIdx.x * blockDim.x + threadIdx.x;
    if (i >= E) return;
    if (i == 0) {
        int b0 = batch[0];
        for (int g = 0; g <= b0; ++g) start[g] = 0;
        int bl = batch[E - 1];
        for (int g = bl + 1; g <= G_NUM; ++g) start[g] = E;
    } else {
        int bp = batch[i - 1], bc = batch[i];
        for (int g = bp + 1; g <= bc; ++g) start[g] = i;
    }
}

__global__ __launch_bounds__(BLOCK) void topk_kernel(
    const float* __restrict__ scores, const void* __restrict__ maskp,
    const int* __restrict__ start, const int* __restrict__ kp,
    const int* __restrict__ flagp, float* __restrict__ out_mask,
    float* __restrict__ out_scores, int E)
{
    __shared__ unsigned long long keys[CAP];
    __shared__ unsigned int hist[256];
    __shared__ unsigned int scan_[256];
    __shared__ unsigned int keptb[CAP / 32];
    __shared__ int cnt;
    __shared__ int bsel;
    __shared__ unsigned int cgt;

    const int g  = blockIdx.x;
    const int s0 = start[g];
    const int s1 = start[g + 1];
    const int len = s1 - s0;
    if (len <= 0) return;

    const int k     = *kp;
    const int mflag = *flagp;
    const int tid   = threadIdx.x;

    auto getmask = [&](int i) -> bool {
        if (mflag == 2) return ((const unsigned char*)maskp)[i] != 0;
        if (mflag == 0) return ((const int*)maskp)[i] != 0;
        return ((const float*)maskp)[i] != 0.0f;
    };

    const bool staged = (len <= CAP);

    if (tid == 0) cnt = 0;
    for (int w = tid; w < CAP / 32; w += BLOCK) keptb[w] = 0u;
    __syncthreads();

    // ---- stage candidate keys (or just count in fallback) ----
    if (staged) {
        for (int i = s0 + tid; i < s1; i += BLOCK) {
            if (getmask(i)) {
                unsigned long long key =
                    ((unsigned long long)order_bits(scores[i]) << 32) |
                    (unsigned long long)(0xFFFFFFFFu - (unsigned)(i - s0));
                keys[atomicAdd(&cnt, 1)] = key;
            }
        }
    } else {
        int lc = 0;
        for (int i = s0 + tid; i < s1; i += BLOCK)
            if (getmask(i)) lc++;
        atomicAdd(&cnt, lc);
    }
    __syncthreads();
    const int m = cnt;

    // ---- exact k-th-largest key via 8-round byte radix select ----
    unsigned long long pivot = 0ull;
    const bool keep_all = (m <= k);
    if (!keep_all) {
        unsigned long long prefix = 0ull;
        int kk = k;
        for (int shift = 56; shift >= 0; shift -= 8) {
            hist[tid] = 0u;
            __syncthreads();
            if (staged) {
                for (int j = tid; j < m; j += BLOCK) {
                    unsigned long long key = keys[j];
                    bool match = (shift == 56) ||
                                 ((key >> (shift + 8)) == (prefix >> (shift + 8)));
                    if (match) atomicAdd(&hist[(unsigned)((key >> shift) & 0xFFull)], 1u);
                }
            } else {
                for (int i = s0 + tid; i < s1; i += BLOCK) {
                    if (!getmask(i)) continue;
                    unsigned long long key =
                        ((unsigned long long)order_bits(scores[i]) << 32) |
                        (unsigned long long)(0xFFFFFFFFu - (unsigned)(i - s0));
                    bool match = (shift == 56) ||
                                 ((key >> (shift + 8)) == (prefix >> (shift + 8)));
                    if (match) atomicAdd(&hist[(unsigned)((key >> shift) & 0xFFull)], 1u);
                }
            }
            __syncthreads();
            // suffix inclusive scan over 256 buckets (Hillis-Steele)
            scan_[tid] = hist[tid];
            __syncthreads();
            for (int off = 1; off < 256; off <<= 1) {
                unsigned int add = (tid + off < 256) ? scan_[tid + off] : 0u;
                __syncthreads();
                scan_[tid] += add;
                __syncthreads();
            }
            unsigned int s_t  = scan_[tid];
            unsigned int s_t1 = (tid < 255) ? scan_[tid + 1] : 0u;
            if ((unsigned)kk > s_t1 && (unsigned)kk <= s_t) { bsel = tid; cgt = s_t1; }
            __syncthreads();
            prefix |= ((unsigned long long)(unsigned)bsel) << shift;
            kk -= (int)cgt;
            __syncthreads();
        }
        pivot = prefix;
    }

    // ---- output ----
    if (staged) {
        for (int j = tid; j < m; j += BLOCK) {
            unsigned long long key = keys[j];
            if (keep_all || key >= pivot) {
                int li = (int)(0xFFFFFFFFu - (unsigned)(key & 0xFFFFFFFFull));
                atomicOr(&keptb[li >> 5], 1u << (li & 31));
            }
        }
        __syncthreads();
        for (int i = s0 + tid; i < s1; i += BLOCK) {
            int li = i - s0;
            bool kept = (keptb[li >> 5] >> (li & 31)) & 1u;
            out_mask[i]   = kept ? 1.0f : 0.0f;
            out_scores[i] = kept ? scores[i] : 0.0f;
        }
    } else {
        for (int i = s0 + tid; i < s1; i += BLOCK) {
            bool c = getmask(i);
            float sc = 0.0f;
            bool kept = false;
            if (c) {
                sc = scores[i];
                unsigned long long key =
                    ((unsigned long long)order_bits(sc) << 32) |
                    (unsigned long long)(0xFFFFFFFFu - (unsigned)(i - s0));
                kept = keep_all || (key >= pivot);
            }
            out_mask[i]   = kept ? 1.0f : 0.0f;
            out_scores[i] = kept ? sc : 0.0f;
        }
    }
}

extern "C" void kernel_launch(void* const* d_in, const int* in_sizes, int n_in,
                              void* d_out, int out_size, void* d_ws, size_t ws_size,
                              hipStream_t stream) {
    const float* scores = (const float*)d_in[0];
    const int*   batch  = (const int*)d_in[1];
    const void*  mask   = d_in[2];
    const int*   kp     = (const int*)d_in[4];
    const int    E      = in_sizes[0];

    float* out_mask   = (float*)d_out;
    float* out_scores = out_mask + E;

    int* flag  = (int*)d_ws;
    int* start = (int*)((char*)d_ws + 256);

    detect_mask_kernel<<<1, 64, 0, stream>>>((const unsigned int*)mask, flag);
    seg_starts_kernel<<<(E + 255) / 256, 256, 0, stream>>>(batch, start, E);
    topk_kernel<<<G_NUM, BLOCK, 0, stream>>>(scores, mask, start, kp, flag,
                                             out_mask, out_scores, E);
}

// Round 2
// 70.933 us; speedup vs baseline: 1.6863x; 1.6863x over previous
//
#include <hip/hip_runtime.h>
#include <stdint.h>

#define G_NUM 4096
#define BLOCK 256
#define CAP   3072   // staged keys per segment (mean seg len 2048, sd ~45 -> 22 sigma)
#define ACT   1152   // compacted active-set capacity (expected ~140 after round 1)

typedef unsigned long long ull;

__device__ __forceinline__ unsigned int order_bits(float f) {
    unsigned int b = __float_as_uint(f);
    return (b & 0x80000000u) ? ~b : (b | 0x80000000u);
}
__device__ __forceinline__ float inv_order_bits(unsigned int ob) {
    return __uint_as_float((ob & 0x80000000u) ? (ob & 0x7FFFFFFFu) : ~ob);
}

// flag: 0 = int32 mask, 1 = float mask, 2 = byte (bool) mask
__global__ void detect_mask_kernel(const unsigned int* __restrict__ m, int* __restrict__ flag) {
    int lane = threadIdx.x;
    bool allI = true, allF = true;
    for (int i = lane; i < 256; i += 64) {
        unsigned int w = m[i];
        if (w > 1u) allI = false;
        if (w != 0u && w != 0x3F800000u) allF = false;
    }
    allI = __all(allI);
    allF = __all(allF);
    if (lane == 0) *flag = allI ? 0 : (allF ? 1 : 2);
}

__global__ void seg_starts_kernel(const int* __restrict__ batch, int* __restrict__ start, int E) {
    int i = blockIdx.x * blockDim.x + threadIdx.x;
    if (i >= E) return;
    if (i == 0) {
        int b0 = batch[0];
        for (int g = 0; g <= b0; ++g) start[g] = 0;
        int bl = batch[E - 1];
        for (int g = bl + 1; g <= G_NUM; ++g) start[g] = E;
    } else {
        int bp = batch[i - 1], bc = batch[i];
        for (int g = bp + 1; g <= bc; ++g) start[g] = i;
    }
}

// 256-bucket suffix scan + k-th bucket select. 2 barriers. Resets *cnt2.
__device__ __forceinline__ void scan_select(
    const unsigned int* hist, unsigned int* wtot, int kk,
    int* bsel_s, unsigned int* cgt_s, int* cnt2, int tid)
{
    unsigned int h = hist[tid];
    unsigned int v = h;
    int lane = tid & 63, wv = tid >> 6;
    #pragma unroll
    for (int off = 1; off < 64; off <<= 1) {
        unsigned int o = __shfl_down(v, off, 64);
        if (lane + off < 64) v += o;
    }
    if (lane == 0) wtot[wv] = v;
    if (tid == 0) *cnt2 = 0;
    __syncthreads();
    unsigned int sfx = v;
    for (int w = wv + 1; w < 4; ++w) sfx += wtot[w];
    if ((unsigned)kk <= sfx && (unsigned)kk > sfx - h) { *bsel_s = tid; *cgt_s = sfx - h; }
    __syncthreads();
}

__global__ __launch_bounds__(BLOCK) void topk_kernel(
    const float* __restrict__ scores, const void* __restrict__ maskp,
    const int* __restrict__ start, const int* __restrict__ kp,
    const int* __restrict__ flagp, float* __restrict__ out_mask,
    float* __restrict__ out_scores, int E)
{
    __shared__ ull keys[CAP];
    __shared__ unsigned short act[2][ACT];
    __shared__ unsigned int hist[256];
    __shared__ unsigned int wtot[4];
    __shared__ unsigned int keptb[CAP / 32];
    __shared__ int cnt, cnt2, bsel_s;
    __shared__ unsigned int cgt_s;
    __shared__ ull pivot_s;

    const int g  = blockIdx.x;
    const int s0 = start[g];
    const int s1 = start[g + 1];
    const int len = s1 - s0;
    if (len <= 0) return;

    const int k     = *kp;
    const int mflag = *flagp;
    const int tid   = threadIdx.x;

    auto getmask = [&](int i) -> bool {
        if (mflag == 2) return ((const unsigned char*)maskp)[i] != 0;
        if (mflag == 0) return ((const int*)maskp)[i] != 0;
        return ((const float*)maskp)[i] != 0.0f;
    };

    if (tid == 0) cnt = 0;
    for (int w = tid; w < CAP / 32; w += BLOCK) keptb[w] = 0u;
    __syncthreads();

    if (len <= CAP) {
        // ---- stage candidate keys into LDS ----
        for (int i = s0 + tid; i < s1; i += BLOCK) {
            if (getmask(i)) {
                ull key = ((ull)order_bits(scores[i]) << 32) |
                          (ull)(0xFFFFFFFFu - (unsigned)(i - s0));
                keys[atomicAdd(&cnt, 1)] = key;
            }
        }
        __syncthreads();
        const int m = cnt;
        const bool keep_all = (m <= k);
        ull pivot = 0ull;

        if (!keep_all) {
            ull prefix = 0ull;
            int kk = k;
            int ccnt = m;
            int compacted = -1;  // -1: no active list; else index of act buffer

            for (int shift = 56; shift >= 0; shift -= 8) {
                if (compacted >= 0 && ccnt <= 64) break;
                hist[tid] = 0u;
                __syncthreads();
                if (compacted < 0) {
                    for (int j = tid; j < m; j += BLOCK) {
                        ull key = keys[j];
                        if (shift == 56 || (key >> (shift + 8)) == (prefix >> (shift + 8)))
                            atomicAdd(&hist[(unsigned)((key >> shift) & 0xFFull)], 1u);
                    }
                } else {
                    for (int j = tid; j < ccnt; j += BLOCK)
                        atomicAdd(&hist[(unsigned)((keys[act[compacted][j]] >> shift) & 0xFFull)], 1u);
                }
                __syncthreads();
                scan_select(hist, wtot, kk, &bsel_s, &cgt_s, &cnt2, tid);
                const int b = bsel_s;
                const unsigned int cgt = cgt_s;
                const int csel = (int)hist[b];

                if (csel <= ACT) {
                    if (compacted < 0) {
                        for (int j = tid; j < m; j += BLOCK) {
                            ull key = keys[j];
                            if ((shift == 56 || (key >> (shift + 8)) == (prefix >> (shift + 8))) &&
                                (unsigned)((key >> shift) & 0xFFull) == (unsigned)b)
                                act[0][atomicAdd(&cnt2, 1)] = (unsigned short)j;
                        }
                        compacted = 0;
                    } else {
                        const int src = compacted, dst = compacted ^ 1;
                        for (int j = tid; j < ccnt; j += BLOCK) {
                            unsigned short aj = act[src][j];
                            if ((unsigned)((keys[aj] >> shift) & 0xFFull) == (unsigned)b)
                                act[dst][atomicAdd(&cnt2, 1)] = aj;
                        }
                        compacted = dst;
                    }
                }
                ccnt = csel;
                prefix |= ((ull)(unsigned)b) << shift;
                kk -= (int)cgt;
                __syncthreads();
            }

            if (compacted < 0) {
                pivot = prefix;  // all 64 bits resolved; keys unique -> exact
            } else {
                if (tid == 0) pivot_s = 0ull;
                __syncthreads();
                if (tid < ccnt) {
                    ull key = keys[act[compacted][tid]];
                    int r = 0;
                    for (int j = 0; j < ccnt; ++j) r += (keys[act[compacted][j]] > key);
                    if (r == kk - 1) pivot_s = key;
                }
                __syncthreads();
                pivot = pivot_s;
            }
        }

        // ---- kept bitmap + score scatter (scores decoded from keys) ----
        for (int j = tid; j < m; j += BLOCK) {
            ull key = keys[j];
            if (keep_all || key >= pivot) {
                unsigned li = 0xFFFFFFFFu - (unsigned)(key & 0xFFFFFFFFull);
                atomicOr(&keptb[li >> 5], 1u << (li & 31));
                out_scores[s0 + (int)li] = inv_order_bits((unsigned)(key >> 32));
            }
        }
        __syncthreads();
        for (int i = s0 + tid; i < s1; i += BLOCK) {
            int li = i - s0;
            bool kept = (keptb[li >> 5] >> (li & 31)) & 1u;
            out_mask[i] = kept ? 1.0f : 0.0f;
            if (!kept) out_scores[i] = 0.0f;
        }
    } else {
        // ---- fallback: global-rescan radix (rare; len > CAP) ----
        int lc = 0;
        for (int i = s0 + tid; i < s1; i += BLOCK)
            if (getmask(i)) lc++;
        atomicAdd(&cnt, lc);
        __syncthreads();
        const int m = cnt;
        const bool keep_all = (m <= k);
        ull pivot = 0ull;
        if (!keep_all) {
            ull prefix = 0ull;
            int kk = k;
            for (int shift = 56; shift >= 0; shift -= 8) {
                hist[tid] = 0u;
                __syncthreads();
                for (int i = s0 + tid; i < s1; i += BLOCK) {
                    if (!getmask(i)) continue;
                    ull key = ((ull)order_bits(scores[i]) << 32) |
                              (ull)(0xFFFFFFFFu - (unsigned)(i - s0));
                    if (shift == 56 || (key >> (shift + 8)) == (prefix >> (shift + 8)))
                        atomicAdd(&hist[(unsigned)((key >> shift) & 0xFFull)], 1u);
                }
                __syncthreads();
                scan_select(hist, wtot, kk, &bsel_s, &cgt_s, &cnt2, tid);
                prefix |= ((ull)(unsigned)bsel_s) << shift;
                kk -= (int)cgt_s;
                __syncthreads();
            }
            pivot = prefix;
        }
        for (int i = s0 + tid; i < s1; i += BLOCK) {
            bool c = getmask(i);
            float sc = 0.0f;
            bool kept = false;
            if (c) {
                sc = scores[i];
                ull key = ((ull)order_bits(sc) << 32) |
                          (ull)(0xFFFFFFFFu - (unsigned)(i - s0));
                kept = keep_all || (key >= pivot);
            }
            out_mask[i]   = kept ? 1.0f : 0.0f;
            out_scores[i] = kept ? sc : 0.0f;
        }
    }
}

extern "C" void kernel_launch(void* const* d_in, const int* in_sizes, int n_in,
                              void* d_out, int out_size, void* d_ws, size_t ws_size,
                              hipStream_t stream) {
    const float* scores = (const float*)d_in[0];
    const int*   batch  = (const int*)d_in[1];
    const void*  mask   = d_in[2];
    const int*   kp     = (const int*)d_in[4];
    const int    E      = in_sizes[0];

    float* out_mask   = (float*)d_out;
    float* out_scores = out_mask + E;

    int* flag  = (int*)d_ws;
    int* start = (int*)((char*)d_ws + 256);

    detect_mask_kernel<<<1, 64, 0, stream>>>((const unsigned int*)mask, flag);
    seg_starts_kernel<<<(E + 255) / 256, 256, 0, stream>>>(batch, start, E);
    topk_kernel<<<G_NUM, BLOCK, 0, stream>>>(scores, mask, start, kp, flag,
                                             out_mask, out_scores, E);
}

// Round 3
// 52.665 us; speedup vs baseline: 2.2712x; 1.3469x over previous
//
#include <hip/hip_runtime.h>
#include <stdint.h>

#define G_NUM 4096
#define BLOCK 256
#define CAP   3072   // max staged segment length (mean 2048, sd ~45 -> 22 sigma)
#define ACT   1152   // compacted active-set capacity

typedef unsigned long long ull;

__device__ __forceinline__ unsigned int order_bits(float f) {
    unsigned int b = __float_as_uint(f);
    return (b & 0x80000000u) ? ~b : (b | 0x80000000u);
}
__device__ __forceinline__ float inv_order_bits(unsigned int ob) {
    return __uint_as_float((ob & 0x80000000u) ? (ob & 0x7FFFFFFFu) : ~ob);
}

// seg_starts (int4-vectorized) + mask dtype detect fused in block 0.
// flag: 0 = int32 mask, 1 = float mask, 2 = byte (bool) mask
__global__ void prep_kernel(const int* __restrict__ batch, int* __restrict__ start,
                            const unsigned int* __restrict__ mraw, int* __restrict__ flag,
                            int E) {
    if (blockIdx.x == 0 && threadIdx.x < 64) {
        int lane = threadIdx.x;
        bool allI = true, allF = true;
        for (int i = lane; i < 256; i += 64) {
            unsigned int w = mraw[i];
            if (w > 1u) allI = false;
            if (w != 0u && w != 0x3F800000u) allF = false;
        }
        allI = __all(allI);
        allF = __all(allF);
        if (lane == 0) *flag = allI ? 0 : (allF ? 1 : 2);
    }
    const int n4 = E >> 2;
    int i4 = blockIdx.x * blockDim.x + threadIdx.x;
    if (i4 >= n4) return;
    int4 b = ((const int4*)batch)[i4];
    int prev = __shfl_up(b.w, 1, 64);
    if ((threadIdx.x & 63) == 0) prev = (i4 == 0) ? -1 : batch[i4 * 4 - 1];
    const int e0 = i4 * 4;
    for (int g = prev + 1; g <= b.x; ++g) start[g] = e0;
    for (int g = b.x + 1; g <= b.y; ++g) start[g] = e0 + 1;
    for (int g = b.y + 1; g <= b.z; ++g) start[g] = e0 + 2;
    for (int g = b.z + 1; g <= b.w; ++g) start[g] = e0 + 3;
    if (i4 == n4 - 1) {
        int last = b.w, e = E & ~3;
        for (int t = 0; t < (E & 3); ++t) {
            int v = batch[e + t];
            for (int g = last + 1; g <= v; ++g) start[g] = e + t;
            last = v;
        }
        for (int g = last + 1; g <= G_NUM; ++g) start[g] = E;
    }
}

// 256-bucket suffix scan + k-th bucket select. Self-clears hist for next round.
__device__ __forceinline__ void scan_select(
    unsigned int* hist, unsigned int* wtot, int kk,
    int* bsel_s, unsigned int* cgt_s, unsigned int* hsel_s, int* cnt2, int tid)
{
    unsigned int h = hist[tid];
    hist[tid] = 0u;                      // own slot only: safe, pre-clears next round
    unsigned int v = h;
    int lane = tid & 63, wv = tid >> 6;
    #pragma unroll
    for (int off = 1; off < 64; off <<= 1) {
        unsigned int o = __shfl_down(v, off, 64);
        if (lane + off < 64) v += o;
    }
    if (lane == 0) wtot[wv] = v;
    if (tid == 0) *cnt2 = 0;
    __syncthreads();
    unsigned int sfx = v;
    for (int w = wv + 1; w < 4; ++w) sfx += wtot[w];
    if ((unsigned)kk <= sfx && (unsigned)kk > sfx - h) {
        *bsel_s = tid; *cgt_s = sfx - h; *hsel_s = h;
    }
    __syncthreads();
}

__global__ __launch_bounds__(BLOCK) void topk_kernel(
    const float* __restrict__ scores, const void* __restrict__ maskp,
    const int* __restrict__ start, const int* __restrict__ kp,
    const int* __restrict__ flagp, float* __restrict__ out_mask,
    float* __restrict__ out_scores, int E)
{
    __shared__ unsigned int keys[CAP];
    __shared__ unsigned short act[2][ACT];
    __shared__ ull candb[CAP / 64];
    __shared__ unsigned int hist[256];
    __shared__ unsigned int wtot[4];
    __shared__ int cnt, cnt2, bsel_s, licut_s;
    __shared__ unsigned int cgt_s, hsel_s, P_s;

    const int g  = blockIdx.x;
    const int s0 = start[g];
    const int s1 = start[g + 1];
    const int len = s1 - s0;
    if (len <= 0) return;

    const int k     = *kp;
    const int mflag = *flagp;
    const int tid   = threadIdx.x;
    const int lane  = tid & 63;
    const int wv    = tid >> 6;

    auto getmask = [&](int i) -> bool {
        if (mflag == 2) return ((const unsigned char*)maskp)[i] != 0;
        if (mflag == 0) return ((const int*)maskp)[i] != 0;
        return ((const float*)maskp)[i] != 0.0f;
    };

    if (k <= 0) {
        for (int i = s0 + tid; i < s1; i += BLOCK) { out_mask[i] = 0.0f; out_scores[i] = 0.0f; }
        return;
    }

    hist[tid] = 0u;
    if (tid == 0) cnt = 0;
    __syncthreads();

    if (len <= CAP) {
        const int iters = (len + BLOCK - 1) / BLOCK;
        unsigned int wcnt = 0;
        // ---- staging: keys positional, candidate bitmap via ballot, fused r1 hist ----
        for (int it = 0; it < iters; ++it) {
            int li = it * BLOCK + tid;
            bool c = false;
            if (li < len) {
                int i = s0 + li;
                c = getmask(i);
                unsigned kb = order_bits(scores[i]);
                keys[li] = kb;
                if (c) atomicAdd(&hist[kb >> 24], 1u);
            }
            ull bal = __ballot(c);
            if (lane == 0) {
                candb[it * 4 + wv] = bal;
                wcnt += __popcll(bal);
            }
        }
        if (lane == 0 && wcnt) atomicAdd(&cnt, (int)wcnt);
        __syncthreads();
        const int m = cnt;
        const bool keep_all = (m <= k);
        unsigned int P = 0u;
        int licut = 0;

        if (!keep_all) {
            unsigned int prefix = 0u;
            int kk = k;
            int ccnt = m;
            int compacted = -1;
            int alen = 0;

            for (int shift = 24; ; shift -= 8) {
                scan_select(hist, wtot, kk, &bsel_s, &cgt_s, &hsel_s, &cnt2, tid);
                const unsigned b   = (unsigned)bsel_s;
                const unsigned cgt = cgt_s;
                const int csel     = (int)hsel_s;

                if (csel <= ACT) {
                    if (compacted < 0) {
                        for (int it = 0; it < iters; ++it) {
                            int li = it * BLOCK + tid;
                            if (li >= len) break;
                            if (!((candb[li >> 6] >> (li & 63)) & 1)) continue;
                            unsigned key = keys[li];
                            if (shift < 24 && (key >> (shift + 8)) != (prefix >> (shift + 8))) continue;
                            if (((key >> shift) & 0xFFu) == b)
                                act[0][atomicAdd(&cnt2, 1)] = (unsigned short)li;
                        }
                        compacted = 0;
                    } else {
                        int src = compacted, dst = src ^ 1;
                        for (int j = tid; j < alen; j += BLOCK) {
                            unsigned short lj = act[src][j];
                            if (((keys[lj] >> shift) & 0xFFu) == b)
                                act[dst][atomicAdd(&cnt2, 1)] = lj;
                        }
                        compacted = dst;
                    }
                    alen = csel;
                }
                prefix |= b << shift;
                kk -= (int)cgt;
                ccnt = csel;
                __syncthreads();
                if (shift == 0 || (compacted >= 0 && ccnt <= 64)) break;

                // ---- build next-round histogram ----
                if (compacted < 0) {
                    for (int it = 0; it < iters; ++it) {
                        int li = it * BLOCK + tid;
                        if (li >= len) break;
                        if (!((candb[li >> 6] >> (li & 63)) & 1)) continue;
                        unsigned key = keys[li];
                        if ((key >> shift) == (prefix >> shift))
                            atomicAdd(&hist[(key >> (shift - 8)) & 0xFFu], 1u);
                    }
                } else {
                    for (int j = tid; j < alen; j += BLOCK)
                        atomicAdd(&hist[(keys[act[compacted][j]] >> (shift - 8)) & 0xFFu], 1u);
                }
                __syncthreads();
            }

            // ---- boundary (P, licut): exact tie-break by local index ----
            if (tid == 0) { P_s = prefix; licut_s = 0x7FFFFFFF; }
            __syncthreads();
            if (compacted >= 0 && ccnt <= 64) {
                if (tid < 64) {  // fresh act, full (key,li) rank in one wave
                    unsigned key = 0u; int li = 0x7FFFFFFF;
                    if (tid < ccnt) { li = act[compacted][tid]; key = keys[li]; }
                    int r = 0;
                    for (int j = 0; j < ccnt; ++j) {
                        unsigned kj = __shfl(key, j, 64);
                        int lj = __shfl(li, j, 64);
                        if (kj > key || (kj == key && lj < li)) r++;
                    }
                    if (tid < ccnt && r == kk - 1) { P_s = key; licut_s = li; }
                }
            } else if (compacted >= 0) {
                // shift==0 exit, class (= keys fully equal to prefix) inside act superset
                for (int e = tid; e < alen; e += BLOCK) {
                    int li = act[compacted][e];
                    if (keys[li] != prefix) continue;
                    int r = 0;
                    for (int j = 0; j < alen; ++j) {
                        int lj = act[compacted][j];
                        if (keys[lj] == prefix && lj < li) r++;
                    }
                    if (r == kk - 1) licut_s = li;
                }
            } else {
                // pathological: never compacted; positional scan of equal-key class
                for (int li = tid; li < len; li += BLOCK) {
                    if (!((candb[li >> 6] >> (li & 63)) & 1)) continue;
                    if (keys[li] != prefix) continue;
                    int r = 0;
                    for (int j = 0; j < len; ++j)
                        if (((candb[j >> 6] >> (j & 63)) & 1) && keys[j] == prefix && j < li) r++;
                    if (r == kk - 1) licut_s = li;
                }
            }
            __syncthreads();
            P = P_s; licut = licut_s;
        }

        // ---- output: all from LDS ----
        for (int it = 0; it < iters; ++it) {
            int li = it * BLOCK + tid;
            if (li >= len) break;
            bool c = (candb[li >> 6] >> (li & 63)) & 1;
            unsigned key = keys[li];
            bool kept = c && (keep_all || key > P || (key == P && li <= licut));
            out_mask[s0 + li]   = kept ? 1.0f : 0.0f;
            out_scores[s0 + li] = kept ? inv_order_bits(key) : 0.0f;
        }
    } else {
        // ---- fallback: global-rescan 64-bit radix (len > CAP; ~never) ----
        int lc = 0;
        for (int i = s0 + tid; i < s1; i += BLOCK)
            if (getmask(i)) lc++;
        atomicAdd(&cnt, lc);
        __syncthreads();
        const int m = cnt;
        const bool keep_all = (m <= k);
        ull pivot = 0ull;
        if (!keep_all) {
            ull prefix = 0ull;
            int kk = k;
            for (int shift = 56; shift >= 0; shift -= 8) {
                for (int i = s0 + tid; i < s1; i += BLOCK) {
                    if (!getmask(i)) continue;
                    ull key = ((ull)order_bits(scores[i]) << 32) |
                              (ull)(0xFFFFFFFFu - (unsigned)(i - s0));
                    if (shift == 56 || (key >> (shift + 8)) == (prefix >> (shift + 8)))
                        atomicAdd(&hist[(unsigned)((key >> shift) & 0xFFull)], 1u);
                }
                __syncthreads();
                scan_select(hist, wtot, kk, &bsel_s, &cgt_s, &hsel_s, &cnt2, tid);
                prefix |= ((ull)(unsigned)bsel_s) << shift;
                kk -= (int)cgt_s;
            }
            pivot = prefix;
        }
        for (int i = s0 + tid; i < s1; i += BLOCK) {
            bool c = getmask(i);
            float sc = 0.0f;
            bool kept = false;
            if (c) {
                sc = scores[i];
                ull key = ((ull)order_bits(sc) << 32) |
                          (ull)(0xFFFFFFFFu - (unsigned)(i - s0));
                kept = keep_all || (key >= pivot);
            }
            out_mask[i]   = kept ? 1.0f : 0.0f;
            out_scores[i] = kept ? sc : 0.0f;
        }
    }
}

extern "C" void kernel_launch(void* const* d_in, const int* in_sizes, int n_in,
                              void* d_out, int out_size, void* d_ws, size_t ws_size,
                              hipStream_t stream) {
    const float* scores = (const float*)d_in[0];
    const int*   batch  = (const int*)d_in[1];
    const void*  mask   = d_in[2];
    const int*   kp     = (const int*)d_in[4];
    const int    E      = in_sizes[0];

    float* out_mask   = (float*)d_out;
    float* out_scores = out_mask + E;

    int* flag  = (int*)d_ws;
    int* start = (int*)((char*)d_ws + 256);

    const int n4 = E >> 2;
    prep_kernel<<<(n4 + BLOCK - 1) / BLOCK, BLOCK, 0, stream>>>(
        batch, start, (const unsigned int*)mask, flag, E);
    topk_kernel<<<G_NUM, BLOCK, 0, stream>>>(scores, mask, start, kp, flag,
                                             out_mask, out_scores, E);
}